// Round 1
// baseline (727.053 us; speedup 1.0000x reference)
//
#include <hip/hip_runtime.h>
#include <cstdint>

typedef _Float16 half8 __attribute__((ext_vector_type(8)));
typedef float f32x4 __attribute__((ext_vector_type(4)));

#define L2E 1.44269504088896340736f

// ---------------------------------------------------------------------------
// convert fp32 -> fp16 (three activation tensors), 8 elems/thread
// ---------------------------------------------------------------------------
__global__ __launch_bounds__(256) void cvt_f32_f16_3(
    const float* __restrict__ s0, const float* __restrict__ s1, const float* __restrict__ s2,
    _Float16* __restrict__ d0, _Float16* __restrict__ d1, _Float16* __restrict__ d2)
{
  const float* src = (blockIdx.z == 0) ? s0 : (blockIdx.z == 1 ? s1 : s2);
  _Float16* dst    = (blockIdx.z == 0) ? d0 : (blockIdx.z == 1 ? d1 : d2);
  size_t i = ((size_t)blockIdx.x * 256 + threadIdx.x) * 8;
  float4 a = *(const float4*)(src + i);
  float4 b = *(const float4*)(src + i + 4);
  half8 o;
  o[0] = (_Float16)a.x; o[1] = (_Float16)a.y; o[2] = (_Float16)a.z; o[3] = (_Float16)a.w;
  o[4] = (_Float16)b.x; o[5] = (_Float16)b.y; o[6] = (_Float16)b.z; o[7] = (_Float16)b.w;
  *(half8*)(dst + i) = o;
}

// ---------------------------------------------------------------------------
// transpose + convert weight: src fp32 [K][N] (ld=N) -> dst fp16 [N][K] (ld=K)
// grid (N/32, K/32), block (32,8)
// ---------------------------------------------------------------------------
__global__ __launch_bounds__(256) void transpose_w(
    const float* __restrict__ src, _Float16* __restrict__ dst, const int N, const int K)
{
  __shared__ float t[32][33];
  const int n0 = blockIdx.x * 32, k0 = blockIdx.y * 32;
  #pragma unroll
  for (int i = 0; i < 4; ++i)
    t[threadIdx.y + i * 8][threadIdx.x] =
        src[(size_t)(k0 + threadIdx.y + i * 8) * N + n0 + threadIdx.x];
  __syncthreads();
  #pragma unroll
  for (int i = 0; i < 4; ++i)
    dst[(size_t)(n0 + threadIdx.y + i * 8) * K + k0 + threadIdx.x] =
        (_Float16)t[threadIdx.x][threadIdx.y + i * 8];
}

// ---------------------------------------------------------------------------
// transpose V (from QKV buffer) -> VT[b][h][d][t], fp16
// grid (2048/32, 64/32, 16), block (32,8)
// ---------------------------------------------------------------------------
__global__ __launch_bounds__(256) void transpose_v(
    const _Float16* __restrict__ QKV, _Float16* __restrict__ VT)
{
  const int bh = blockIdx.z;
  const int bb = bh >> 3, h = bh & 7;
  const int t0 = blockIdx.x * 32, d0 = blockIdx.y * 32;
  __shared__ _Float16 t[32][33];
  const _Float16* src = QKV + (size_t)(bb * 2048) * 3072 + 2560 + h * 64;
  #pragma unroll
  for (int i = 0; i < 4; ++i)
    t[threadIdx.y + i * 8][threadIdx.x] =
        src[(size_t)(t0 + threadIdx.y + i * 8) * 3072 + d0 + threadIdx.x];
  __syncthreads();
  _Float16* dst = VT + ((size_t)(bb * 8 + h) * 64) * 2048;
  #pragma unroll
  for (int i = 0; i < 4; ++i)
    dst[(size_t)(d0 + threadIdx.y + i * 8) * 2048 + t0 + threadIdx.x] =
        t[threadIdx.x][threadIdx.y + i * 8];
}

// ---------------------------------------------------------------------------
// fp16 GEMM, C = A * B^T(+bias). 128x128 tile, BK=64, 4 waves (64x64 each).
// A: [M][K] fp16 (ld=K), Bt: [N][K] fp16 (ld=K).
// MODE 0: QKV projection -> fp16 out [4096][3072], A/bias selected per n-block
// MODE 1: O projection   -> fp32 out [4096][2048]
// LDS XOR swizzle: byte ^= ((row&7)<<4) within 128B rows (conflict-free b128).
// ---------------------------------------------------------------------------
template<int MODE>
__global__ __launch_bounds__(256) void gemm_f16(
    const _Float16* __restrict__ Aq, const _Float16* __restrict__ Ak, const _Float16* __restrict__ Av,
    const _Float16* __restrict__ Bt,
    const float* __restrict__ bias0, const float* __restrict__ bias1, const float* __restrict__ bias2,
    _Float16* __restrict__ Ch, float* __restrict__ Cf, const int K, const int N)
{
  const int m0 = blockIdx.x * 128;
  const int n0 = blockIdx.y * 128;
  const _Float16* A = Aq;
  if constexpr (MODE == 0) { if (n0 >= 2560) A = Av; else if (n0 >= 2048) A = Ak; }
  const int tid = threadIdx.x;
  const int lane = tid & 63;
  const int w = tid >> 6;
  const int wr = w >> 1, wc = w & 1;
  const int lo = lane & 15, hi = lane >> 4;

  __shared__ __align__(16) _Float16 Asm[128 * 64];
  __shared__ __align__(16) _Float16 Bsm[128 * 64];

  f32x4 acc[4][4];
  #pragma unroll
  for (int i = 0; i < 4; ++i)
    #pragma unroll
    for (int j = 0; j < 4; ++j)
      acc[i][j] = (f32x4){0.f, 0.f, 0.f, 0.f};

  const int srow = tid >> 3;  // 0..31
  const int soct = tid & 7;   // 0..7

  for (int k0 = 0; k0 < K; k0 += 64) {
    uint4 areg[4], breg[4];
    #pragma unroll
    for (int u = 0; u < 4; ++u) {
      const int row = srow + u * 32;
      areg[u] = *(const uint4*)(A  + (size_t)(m0 + row) * K + k0 + soct * 8);
      breg[u] = *(const uint4*)(Bt + (size_t)(n0 + row) * K + k0 + soct * 8);
    }
    __syncthreads();
    #pragma unroll
    for (int u = 0; u < 4; ++u) {
      const int row = srow + u * 32;
      const int off = row * 128 + 16 * (soct ^ (row & 7));
      *(uint4*)((char*)Asm + off) = areg[u];
      *(uint4*)((char*)Bsm + off) = breg[u];
    }
    __syncthreads();
    #pragma unroll
    for (int kp = 0; kp < 2; ++kp) {
      half8 af[4], bf[4];
      #pragma unroll
      for (int i = 0; i < 4; ++i) {
        const int ra = wr * 64 + i * 16 + lo;
        af[i] = *(const half8*)((const char*)Asm + ra * 128 + ((kp * 64 + hi * 16) ^ ((ra & 7) << 4)));
        const int rb = wc * 64 + i * 16 + lo;
        bf[i] = *(const half8*)((const char*)Bsm + rb * 128 + ((kp * 64 + hi * 16) ^ ((rb & 7) << 4)));
      }
      #pragma unroll
      for (int i = 0; i < 4; ++i)
        #pragma unroll
        for (int j = 0; j < 4; ++j)
          acc[i][j] = __builtin_amdgcn_mfma_f32_16x16x32_f16(af[i], bf[j], acc[i][j], 0, 0, 0);
    }
  }

  // epilogue: C/D layout col = lane&15, row = 4*(lane>>4)+reg
  #pragma unroll
  for (int i = 0; i < 4; ++i) {
    const int rrow = m0 + wr * 64 + i * 16 + hi * 4;
    #pragma unroll
    for (int j = 0; j < 4; ++j) {
      const int col = n0 + wc * 64 + j * 16 + lo;
      float bias;
      if constexpr (MODE == 0)
        bias = (col < 2048) ? bias0[col] : (col < 2560 ? bias1[col - 2048] : bias2[col - 2560]);
      else
        bias = bias0[col];
      #pragma unroll
      for (int r = 0; r < 4; ++r) {
        const float v = acc[i][j][r] + bias;
        if constexpr (MODE == 0) Ch[(size_t)(rrow + r) * N + col] = (_Float16)v;
        else                     Cf[(size_t)(rrow + r) * N + col] = v;
      }
    }
  }
}

// ---------------------------------------------------------------------------
// Flash attention: grid (32 qtiles, 32 qheads, 2 batch), 256 threads (4 waves).
// Each wave owns 16 q-rows; K-tile loop of 64 keys. Online softmax in fp32.
// Q,K from QKV fp16 buffer [4096][3072]; V^T from VT [b][h][64][2048].
// Output ao fp16 [4096][2048] (head-concat order col = qh*64+d).
// ---------------------------------------------------------------------------
__global__ __launch_bounds__(256) void attn_fwd(
    const _Float16* __restrict__ QKV, const _Float16* __restrict__ VT,
    _Float16* __restrict__ AO)
{
  const int qt = blockIdx.x, qh = blockIdx.y, b = blockIdx.z;
  const int h = qh & 7;
  const int tid = threadIdx.x;
  const int lane = tid & 63;
  const int w = tid >> 6;
  const int lo = lane & 15, hi = lane >> 4;

  __shared__ __align__(16) _Float16 Ksm[64 * 64];
  __shared__ __align__(16) _Float16 Vsm[64 * 64];
  __shared__ __align__(16) _Float16 Psm[4 * 16 * 64];

  // Q fragments (held in registers for whole kernel)
  const size_t qrow = (size_t)(b * 2048 + qt * 64 + w * 16 + lo);
  half8 qf[2];
  #pragma unroll
  for (int kp = 0; kp < 2; ++kp)
    qf[kp] = *(const half8*)(QKV + qrow * 3072 + qh * 64 + kp * 32 + hi * 8);

  f32x4 oacc[4];
  #pragma unroll
  for (int j = 0; j < 4; ++j) oacc[j] = (f32x4){0.f, 0.f, 0.f, 0.f};
  float mrow[4], lrow[4];
  #pragma unroll
  for (int r = 0; r < 4; ++r) { mrow[r] = -1e30f; lrow[r] = 0.f; }

  const int srow = tid >> 3;  // 0..31
  const int soct = tid & 7;   // 0..7
  const _Float16* Kbase = QKV + 2048 + h * 64;
  const _Float16* Vbase = VT + ((size_t)(b * 8 + h) * 64) * 2048;

  for (int t0 = 0; t0 < 2048; t0 += 64) {
    uint4 kreg[2], vreg[2];
    #pragma unroll
    for (int u = 0; u < 2; ++u) {
      const int row = srow + u * 32;
      kreg[u] = *(const uint4*)(Kbase + (size_t)(b * 2048 + t0 + row) * 3072 + soct * 8);
      vreg[u] = *(const uint4*)(Vbase + (size_t)row * 2048 + t0 + soct * 8);
    }
    __syncthreads();
    #pragma unroll
    for (int u = 0; u < 2; ++u) {
      const int row = srow + u * 32;
      const int off = row * 128 + 16 * (soct ^ (row & 7));
      *(uint4*)((char*)Ksm + off) = kreg[u];
      *(uint4*)((char*)Vsm + off) = vreg[u];
    }
    __syncthreads();

    // S = Q K^T
    f32x4 sacc[4];
    #pragma unroll
    for (int j = 0; j < 4; ++j) sacc[j] = (f32x4){0.f, 0.f, 0.f, 0.f};
    #pragma unroll
    for (int j = 0; j < 4; ++j) {
      #pragma unroll
      for (int kp = 0; kp < 2; ++kp) {
        const int row = j * 16 + lo;
        half8 kf = *(const half8*)((const char*)Ksm + row * 128 + ((kp * 64 + hi * 16) ^ ((row & 7) << 4)));
        sacc[j] = __builtin_amdgcn_mfma_f32_16x16x32_f16(qf[kp], kf, sacc[j], 0, 0, 0);
      }
    }
    float sv[4][4];
    #pragma unroll
    for (int j = 0; j < 4; ++j)
      #pragma unroll
      for (int r = 0; r < 4; ++r) sv[j][r] = sacc[j][r] * 0.125f;

    // row max (cols live in 16-lane group; rows = 4*hi + r)
    float pmax[4];
    #pragma unroll
    for (int r = 0; r < 4; ++r)
      pmax[r] = fmaxf(fmaxf(sv[0][r], sv[1][r]), fmaxf(sv[2][r], sv[3][r]));
    #pragma unroll
    for (int m = 1; m < 16; m <<= 1)
      #pragma unroll
      for (int r = 0; r < 4; ++r) pmax[r] = fmaxf(pmax[r], __shfl_xor(pmax[r], m));

    float mnew[4], corr[4], psum[4];
    #pragma unroll
    for (int r = 0; r < 4; ++r) {
      mnew[r] = fmaxf(mrow[r], pmax[r]);
      corr[r] = exp2f((mrow[r] - mnew[r]) * L2E);
      mrow[r] = mnew[r];
      psum[r] = 0.f;
    }
    // P = exp(S - m), write fp16 to per-wave swizzled LDS
    char* Pw = (char*)Psm + w * 2048;
    #pragma unroll
    for (int j = 0; j < 4; ++j) {
      #pragma unroll
      for (int r = 0; r < 4; ++r) {
        const float p = exp2f((sv[j][r] - mnew[r]) * L2E);
        psum[r] += p;
        const int row = 4 * hi + r;
        const int cb = (j * 32 + lo * 2) ^ ((row & 7) << 4);
        *(_Float16*)(Pw + row * 128 + cb) = (_Float16)p;
      }
    }
    #pragma unroll
    for (int m = 1; m < 16; m <<= 1)
      #pragma unroll
      for (int r = 0; r < 4; ++r) psum[r] += __shfl_xor(psum[r], m);
    #pragma unroll
    for (int r = 0; r < 4; ++r) lrow[r] = lrow[r] * corr[r] + psum[r];
    #pragma unroll
    for (int j = 0; j < 4; ++j)
      #pragma unroll
      for (int r = 0; r < 4; ++r) oacc[j][r] *= corr[r];

    // PV: A-frag = P (per-wave, same-wave LDS ordering; no barrier needed)
    half8 pf[2];
    #pragma unroll
    for (int kp = 0; kp < 2; ++kp)
      pf[kp] = *(const half8*)(Pw + lo * 128 + ((kp * 64 + hi * 16) ^ ((lo & 7) << 4)));
    #pragma unroll
    for (int j = 0; j < 4; ++j) {
      #pragma unroll
      for (int kp = 0; kp < 2; ++kp) {
        const int row = j * 16 + lo;
        half8 vf = *(const half8*)((const char*)Vsm + row * 128 + ((kp * 64 + hi * 16) ^ ((row & 7) << 4)));
        oacc[j] = __builtin_amdgcn_mfma_f32_16x16x32_f16(pf[kp], vf, oacc[j], 0, 0, 0);
      }
    }
    __syncthreads();
  }

  float inv[4];
  #pragma unroll
  for (int r = 0; r < 4; ++r) inv[r] = 1.f / lrow[r];
  #pragma unroll
  for (int j = 0; j < 4; ++j) {
    #pragma unroll
    for (int r = 0; r < 4; ++r) {
      const float v = oacc[j][r] * inv[r];
      AO[(size_t)(b * 2048 + qt * 64 + w * 16 + 4 * hi + r) * 2048 + qh * 64 + j * 16 + lo] =
          (_Float16)v;
    }
  }
}

// ---------------------------------------------------------------------------
extern "C" void kernel_launch(void* const* d_in, const int* in_sizes, int n_in,
                              void* d_out, int out_size, void* d_ws, size_t ws_size,
                              hipStream_t stream) {
  const float* query = (const float*)d_in[0];
  const float* key   = (const float*)d_in[1];
  const float* value = (const float*)d_in[2];
  const float* Wq = (const float*)d_in[3];
  const float* bq = (const float*)d_in[4];
  const float* Wk = (const float*)d_in[5];
  const float* bk = (const float*)d_in[6];
  const float* Wv = (const float*)d_in[7];
  const float* bv = (const float*)d_in[8];
  const float* Wo = (const float*)d_in[9];
  const float* bo = (const float*)d_in[10];
  float* out = (float*)d_out;

  char* ws = (char*)d_ws;
  _Float16* qh    = (_Float16*)(ws);                         // [4096][2048] 16.78 MB
  _Float16* kh    = (_Float16*)(ws + 16777216);              // [4096][2048]
  _Float16* vh    = (_Float16*)(ws + 33554432);              // [4096][2048]
  _Float16* WqkvT = (_Float16*)(ws + 50331648);              // [3072][2048] 12.58 MB
  _Float16* WoT   = (_Float16*)(ws + 62914560);              // [2048][2048]  8.39 MB
  _Float16* QKVh  = (_Float16*)(ws + 71303168);              // [4096][3072] 25.17 MB
  _Float16* VT    = (_Float16*)(ws + 96468992);              // [2][8][64][2048] 4.19 MB
  _Float16* aoh   = (_Float16*)(ws + 100663296);             // [4096][2048] 16.78 MB
  // total 117,440,512 B

  // 1. convert activations to fp16
  cvt_f32_f16_3<<<dim3(4096, 1, 3), 256, 0, stream>>>(query, key, value, qh, kh, vh);
  // 2. transpose + convert weights (fp16 [N][K])
  transpose_w<<<dim3(64, 64), dim3(32, 8), 0, stream>>>(Wq, WqkvT, 2048, 2048);
  transpose_w<<<dim3(16, 64), dim3(32, 8), 0, stream>>>(Wk, WqkvT + (size_t)2048 * 2048, 512, 2048);
  transpose_w<<<dim3(16, 64), dim3(32, 8), 0, stream>>>(Wv, WqkvT + (size_t)2560 * 2048, 512, 2048);
  transpose_w<<<dim3(64, 64), dim3(32, 8), 0, stream>>>(Wo, WoT, 2048, 2048);
  // 3. fused QKV projection -> QKVh fp16 [4096][3072]
  gemm_f16<0><<<dim3(32, 24), 256, 0, stream>>>(qh, kh, vh, WqkvT, bq, bk, bv,
                                                QKVh, nullptr, 2048, 3072);
  // 4. V^T for PV matmul
  transpose_v<<<dim3(64, 2, 16), dim3(32, 8), 0, stream>>>(QKVh, VT);
  // 5. flash attention -> aoh fp16 [4096][2048]
  attn_fwd<<<dim3(32, 32, 2), 256, 0, stream>>>(QKVh, VT, aoh);
  // 6. output projection (+bo) -> fp32 d_out
  gemm_f16<1><<<dim3(32, 16), 256, 0, stream>>>(aoh, nullptr, nullptr, WoT, bo,
                                                nullptr, nullptr, nullptr, out, 2048, 2048);
}

// Round 2
// 511.449 us; speedup vs baseline: 1.4216x; 1.4216x over previous
//
#include <hip/hip_runtime.h>
#include <cstdint>

typedef _Float16 half2v __attribute__((ext_vector_type(2)));
typedef _Float16 half4 __attribute__((ext_vector_type(4)));
typedef _Float16 half8 __attribute__((ext_vector_type(8)));
typedef float f32x4 __attribute__((ext_vector_type(4)));
typedef float f32x16 __attribute__((ext_vector_type(16)));

#define L2E 1.44269504088896340736f

__device__ __forceinline__ void gl16(const void* g, void* l) {
  __builtin_amdgcn_global_load_lds(
      (const __attribute__((address_space(1))) void*)g,
      (__attribute__((address_space(3))) void*)l, 16, 0, 0);
}

__device__ __forceinline__ uint32_t pk2(float a, float b) {
  return __builtin_bit_cast(uint32_t, __builtin_amdgcn_cvt_pkrtz(a, b));
}

__device__ __forceinline__ void plswap(uint32_t& x, uint32_t& y) {
  auto r = __builtin_amdgcn_permlane32_swap((int)x, (int)y, false, false);
  x = (uint32_t)r[0];
  y = (uint32_t)r[1];
}

__device__ __forceinline__ f32x16 zero16() {
  f32x16 z;
  #pragma unroll
  for (int r = 0; r < 16; ++r) z[r] = 0.0f;
  return z;
}

// ---------------------------------------------------------------------------
// convert fp32 -> fp16 (three activation tensors), 8 elems/thread
// ---------------------------------------------------------------------------
__global__ __launch_bounds__(256) void cvt_f32_f16_3(
    const float* __restrict__ s0, const float* __restrict__ s1, const float* __restrict__ s2,
    _Float16* __restrict__ d0, _Float16* __restrict__ d1, _Float16* __restrict__ d2)
{
  const float* src = (blockIdx.z == 0) ? s0 : (blockIdx.z == 1 ? s1 : s2);
  _Float16* dst    = (blockIdx.z == 0) ? d0 : (blockIdx.z == 1 ? d1 : d2);
  size_t i = ((size_t)blockIdx.x * 256 + threadIdx.x) * 8;
  float4 a = *(const float4*)(src + i);
  float4 b = *(const float4*)(src + i + 4);
  half8 o;
  o[0] = (_Float16)a.x; o[1] = (_Float16)a.y; o[2] = (_Float16)a.z; o[3] = (_Float16)a.w;
  o[4] = (_Float16)b.x; o[5] = (_Float16)b.y; o[6] = (_Float16)b.z; o[7] = (_Float16)b.w;
  *(half8*)(dst + i) = o;
}

// ---------------------------------------------------------------------------
// transpose + convert weight: src fp32 [K][N] (ld=N) -> dst fp16 [N][K] (ld=K)
// ---------------------------------------------------------------------------
__global__ __launch_bounds__(256) void transpose_w(
    const float* __restrict__ src, _Float16* __restrict__ dst, const int N, const int K)
{
  __shared__ float t[32][33];
  const int n0 = blockIdx.x * 32, k0 = blockIdx.y * 32;
  #pragma unroll
  for (int i = 0; i < 4; ++i)
    t[threadIdx.y + i * 8][threadIdx.x] =
        src[(size_t)(k0 + threadIdx.y + i * 8) * N + n0 + threadIdx.x];
  __syncthreads();
  #pragma unroll
  for (int i = 0; i < 4; ++i)
    dst[(size_t)(n0 + threadIdx.y + i * 8) * K + k0 + threadIdx.x] =
        (_Float16)t[threadIdx.x][threadIdx.y + i * 8];
}

// ---------------------------------------------------------------------------
// transpose V (from QKV buffer) -> VT[b][h][d][t], fp16
// ---------------------------------------------------------------------------
__global__ __launch_bounds__(256) void transpose_v(
    const _Float16* __restrict__ QKV, _Float16* __restrict__ VT)
{
  const int bh = blockIdx.z;
  const int bb = bh >> 3, h = bh & 7;
  const int t0 = blockIdx.x * 32, d0 = blockIdx.y * 32;
  __shared__ _Float16 t[32][33];
  const _Float16* src = QKV + (size_t)(bb * 2048) * 3072 + 2560 + h * 64;
  #pragma unroll
  for (int i = 0; i < 4; ++i)
    t[threadIdx.y + i * 8][threadIdx.x] =
        src[(size_t)(t0 + threadIdx.y + i * 8) * 3072 + d0 + threadIdx.x];
  __syncthreads();
  _Float16* dst = VT + ((size_t)(bb * 8 + h) * 64) * 2048;
  #pragma unroll
  for (int i = 0; i < 4; ++i)
    dst[(size_t)(d0 + threadIdx.y + i * 8) * 2048 + t0 + threadIdx.x] =
        t[threadIdx.x][threadIdx.y + i * 8];
}

// ---------------------------------------------------------------------------
// fp16 GEMM, C = A * B^T(+bias). 128x128 tile, BK=64, 4 waves (64x64 each).
// (unchanged from R1 — passed)
// ---------------------------------------------------------------------------
template<int MODE>
__global__ __launch_bounds__(256) void gemm_f16(
    const _Float16* __restrict__ Aq, const _Float16* __restrict__ Ak, const _Float16* __restrict__ Av,
    const _Float16* __restrict__ Bt,
    const float* __restrict__ bias0, const float* __restrict__ bias1, const float* __restrict__ bias2,
    _Float16* __restrict__ Ch, float* __restrict__ Cf, const int K, const int N)
{
  const int m0 = blockIdx.x * 128;
  const int n0 = blockIdx.y * 128;
  const _Float16* A = Aq;
  if constexpr (MODE == 0) { if (n0 >= 2560) A = Av; else if (n0 >= 2048) A = Ak; }
  const int tid = threadIdx.x;
  const int lane = tid & 63;
  const int w = tid >> 6;
  const int wr = w >> 1, wc = w & 1;
  const int lo = lane & 15, hi = lane >> 4;

  __shared__ __align__(16) _Float16 Asm[128 * 64];
  __shared__ __align__(16) _Float16 Bsm[128 * 64];

  f32x4 acc[4][4];
  #pragma unroll
  for (int i = 0; i < 4; ++i)
    #pragma unroll
    for (int j = 0; j < 4; ++j)
      acc[i][j] = (f32x4){0.f, 0.f, 0.f, 0.f};

  const int srow = tid >> 3;
  const int soct = tid & 7;

  for (int k0 = 0; k0 < K; k0 += 64) {
    uint4 areg[4], breg[4];
    #pragma unroll
    for (int u = 0; u < 4; ++u) {
      const int row = srow + u * 32;
      areg[u] = *(const uint4*)(A  + (size_t)(m0 + row) * K + k0 + soct * 8);
      breg[u] = *(const uint4*)(Bt + (size_t)(n0 + row) * K + k0 + soct * 8);
    }
    __syncthreads();
    #pragma unroll
    for (int u = 0; u < 4; ++u) {
      const int row = srow + u * 32;
      const int off = row * 128 + 16 * (soct ^ (row & 7));
      *(uint4*)((char*)Asm + off) = areg[u];
      *(uint4*)((char*)Bsm + off) = breg[u];
    }
    __syncthreads();
    #pragma unroll
    for (int kp = 0; kp < 2; ++kp) {
      half8 af[4], bf[4];
      #pragma unroll
      for (int i = 0; i < 4; ++i) {
        const int ra = wr * 64 + i * 16 + lo;
        af[i] = *(const half8*)((const char*)Asm + ra * 128 + ((kp * 64 + hi * 16) ^ ((ra & 7) << 4)));
        const int rb = wc * 64 + i * 16 + lo;
        bf[i] = *(const half8*)((const char*)Bsm + rb * 128 + ((kp * 64 + hi * 16) ^ ((rb & 7) << 4)));
      }
      #pragma unroll
      for (int i = 0; i < 4; ++i)
        #pragma unroll
        for (int j = 0; j < 4; ++j)
          acc[i][j] = __builtin_amdgcn_mfma_f32_16x16x32_f16(af[i], bf[j], acc[i][j], 0, 0, 0);
    }
  }

  #pragma unroll
  for (int i = 0; i < 4; ++i) {
    const int rrow = m0 + wr * 64 + i * 16 + hi * 4;
    #pragma unroll
    for (int j = 0; j < 4; ++j) {
      const int col = n0 + wc * 64 + j * 16 + lo;
      float bias;
      if constexpr (MODE == 0)
        bias = (col < 2048) ? bias0[col] : (col < 2560 ? bias1[col - 2048] : bias2[col - 2560]);
      else
        bias = bias0[col];
      #pragma unroll
      for (int r = 0; r < 4; ++r) {
        const float v = acc[i][j][r] + bias;
        if constexpr (MODE == 0) Ch[(size_t)(rrow + r) * N + col] = (_Float16)v;
        else                     Cf[(size_t)(rrow + r) * N + col] = v;
      }
    }
  }
}

// ---------------------------------------------------------------------------
// Flash attention v2: swapped QK^T + in-register softmax (T12 structure).
// grid: 512 blocks linear (XCD-swizzled), 256 threads = 4 waves.
// Block covers 256 q-rows of one (b, qh); wave owns 64 rows (qb=2 x 32).
// KV tile = 64 keys, double-buffered LDS via global_load_lds with
// pre-swizzled per-lane source (XOR swizzle byte ^= (row&7)<<4).
// mfma_f32_32x32x16_f16: A row=l&31,k=8*(l>>5)+e; B col=l&31,k=8*(l>>5)+e;
// C/D col=l&31,row=(reg&3)+8*(reg>>2)+4*(l>>5).
// ---------------------------------------------------------------------------
__global__ __launch_bounds__(256, 2) void attn_fwd2(
    const _Float16* __restrict__ QKV, const _Float16* __restrict__ VT,
    _Float16* __restrict__ AO)
{
  // XCD swizzle: chunks of 32 consecutive work-ids (one (b,h) group) per XCD
  const int wg = blockIdx.x;
  const int work = (wg & 7) * 64 + (wg >> 3);
  const int bh = work >> 5;
  const int b = bh >> 3, h = bh & 7;
  const int rem = work & 31;
  const int qh = (rem >> 3) * 8 + h;
  const int qt = rem & 7;

  const int tid = threadIdx.x;
  const int lane = tid & 63;
  const int w = tid >> 6;
  const int l31 = lane & 31;
  const int hi5 = lane >> 5;
  const int r7 = l31 & 7;

  __shared__ __align__(1024) char sm[2][2][8192];  // [buf][K/V][64 rows x 128B]

  const float SCALE = 0.125f * L2E;

  // Q fragments (B-operand): lane holds Q[q=l31][d = s*16 + hi5*8 + e]
  const int qrow0 = b * 2048 + qt * 256 + w * 64 + l31;
  half8 qf[2][4];
  #pragma unroll
  for (int qb = 0; qb < 2; ++qb) {
    const _Float16* qp = QKV + (size_t)(qrow0 + qb * 32) * 3072 + qh * 64 + hi5 * 8;
    #pragma unroll
    for (int s = 0; s < 4; ++s)
      qf[qb][s] = *(const half8*)(qp + s * 16);
  }

  // staging addresses: lane covers (row-in-8 li, col-slot lc), swizzled source
  const int li = lane >> 3;
  const int lc = lane & 7;
  const int kslot = lc ^ li;          // (row&7)==li for all staged rows
  const int w16li = w * 16 + li;
  const _Float16* Ksrc = QKV + ((size_t)(b * 2048 + w16li)) * 3072 + 2048 + h * 64 + kslot * 8;
  const _Float16* Vsrc = VT + ((size_t)(b * 8 + h) * 64 + w16li) * 2048 + kslot * 8;

  f32x16 oa[2][2];   // [i d-block][qb]
  #pragma unroll
  for (int i = 0; i < 2; ++i)
    #pragma unroll
    for (int qb = 0; qb < 2; ++qb) oa[i][qb] = zero16();
  float mreg[2] = {-3.0e38f, -3.0e38f};
  float lreg[2] = {0.f, 0.f};

  // prologue: stage tile 0 into buf 0
  {
    char* kd = &sm[0][0][0] + w * 2048;
    char* vd = &sm[0][1][0] + w * 2048;
    gl16(Ksrc, kd);
    gl16(Ksrc + (size_t)8 * 3072, kd + 1024);
    gl16(Vsrc, vd);
    gl16(Vsrc + (size_t)8 * 2048, vd + 1024);
  }
  __syncthreads();

  int cur = 0;
  for (int t = 0; t < 32; ++t) {
    // stage next tile into buf cur^1 (issued before compute; drained by barrier)
    if (t < 31) {
      const int t0 = (t + 1) * 64;
      char* kd = &sm[cur ^ 1][0][0] + w * 2048;
      char* vd = &sm[cur ^ 1][1][0] + w * 2048;
      const _Float16* kg = Ksrc + (size_t)t0 * 3072;
      const _Float16* vg = Vsrc + t0;
      gl16(kg, kd);
      gl16(kg + (size_t)8 * 3072, kd + 1024);
      gl16(vg, vd);
      gl16(vg + (size_t)8 * 2048, vd + 1024);
    }

    const char* Kb = &sm[cur][0][0];
    const char* Vb = &sm[cur][1][0];

    // S^T = K Q^T  (rows = keys, cols = q)
    f32x16 sa[2][2];
    #pragma unroll
    for (int j = 0; j < 2; ++j)
      #pragma unroll
      for (int qb = 0; qb < 2; ++qb) sa[j][qb] = zero16();
    #pragma unroll
    for (int s = 0; s < 4; ++s) {
      #pragma unroll
      for (int j = 0; j < 2; ++j) {
        const int kr = j * 32 + l31;
        half8 kf = *(const half8*)(Kb + kr * 128 + (((2 * s + hi5) ^ r7) << 4));
        sa[j][0] = __builtin_amdgcn_mfma_f32_32x32x16_f16(kf, qf[0][s], sa[j][0], 0, 0, 0);
        sa[j][1] = __builtin_amdgcn_mfma_f32_32x32x16_f16(kf, qf[1][s], sa[j][1], 0, 0, 0);
      }
    }

    // online softmax: per-lane scalars (q = l31); pair lane^32 holds other keys
    #pragma unroll
    for (int qb = 0; qb < 2; ++qb) {
      float pm = -3.0e38f;
      #pragma unroll
      for (int j = 0; j < 2; ++j)
        #pragma unroll
        for (int r = 0; r < 16; ++r) {
          const float v = sa[j][qb][r] * SCALE;
          sa[j][qb][r] = v;
          pm = fmaxf(pm, v);
        }
      pm = fmaxf(pm, __shfl_xor(pm, 32));
      const float mnew = fmaxf(mreg[qb], pm);
      const float corr = __builtin_amdgcn_exp2f(mreg[qb] - mnew);
      mreg[qb] = mnew;
      float ps = 0.f;
      #pragma unroll
      for (int j = 0; j < 2; ++j)
        #pragma unroll
        for (int r = 0; r < 16; ++r) {
          const float p = __builtin_amdgcn_exp2f(sa[j][qb][r] - mnew);
          sa[j][qb][r] = p;
          ps += p;
        }
      ps += __shfl_xor(ps, 32);
      lreg[qb] = lreg[qb] * corr + ps;
      #pragma unroll
      for (int i = 0; i < 2; ++i)
        #pragma unroll
        for (int r = 0; r < 16; ++r)
          oa[i][qb][r] *= corr;
    }

    // pack P -> fp16 B-frags via cvt_pkrtz + permlane32_swap (T12)
    uint32_t pw[2][4][4];
    #pragma unroll
    for (int qb = 0; qb < 2; ++qb)
      #pragma unroll
      for (int j = 0; j < 2; ++j)
        #pragma unroll
        for (int hf = 0; hf < 2; ++hf) {
          const int rb = hf * 8;
          uint32_t w0 = pk2(sa[j][qb][rb + 0], sa[j][qb][rb + 1]);
          uint32_t w1 = pk2(sa[j][qb][rb + 2], sa[j][qb][rb + 3]);
          uint32_t w2 = pk2(sa[j][qb][rb + 4], sa[j][qb][rb + 5]);
          uint32_t w3 = pk2(sa[j][qb][rb + 6], sa[j][qb][rb + 7]);
          plswap(w0, w2);   // -> e01, e45
          plswap(w1, w3);   // -> e23, e67
          const int s = 2 * j + hf;
          pw[qb][s][0] = w0; pw[qb][s][1] = w1; pw[qb][s][2] = w2; pw[qb][s][3] = w3;
        }

    // PV: O^T += V^T P^T
    #pragma unroll
    for (int s = 0; s < 4; ++s) {
      union { uint32_t u[4]; half8 h; } p0, p1;
      #pragma unroll
      for (int u = 0; u < 4; ++u) { p0.u[u] = pw[0][s][u]; p1.u[u] = pw[1][s][u]; }
      #pragma unroll
      for (int i = 0; i < 2; ++i) {
        const int vr = i * 32 + l31;
        half8 vf = *(const half8*)(Vb + vr * 128 + (((2 * s + hi5) ^ r7) << 4));
        oa[i][0] = __builtin_amdgcn_mfma_f32_32x32x16_f16(vf, p0.h, oa[i][0], 0, 0, 0);
        oa[i][1] = __builtin_amdgcn_mfma_f32_32x32x16_f16(vf, p1.h, oa[i][1], 0, 0, 0);
      }
    }

    __syncthreads();
    cur ^= 1;
  }

  // epilogue: O^T[d][q] -> AO[q][qh*64+d], 8B contiguous stores
  #pragma unroll
  for (int qb = 0; qb < 2; ++qb) {
    const float inv = 1.0f / lreg[qb];
    const int row = qrow0 + qb * 32;
    #pragma unroll
    for (int i = 0; i < 2; ++i) {
      _Float16* dst = AO + (size_t)row * 2048 + qh * 64 + i * 32 + hi5 * 4;
      #pragma unroll
      for (int q = 0; q < 4; ++q) {
        union { uint32_t u[2]; half4 h4; } o;
        o.u[0] = pk2(oa[i][qb][4 * q + 0] * inv, oa[i][qb][4 * q + 1] * inv);
        o.u[1] = pk2(oa[i][qb][4 * q + 2] * inv, oa[i][qb][4 * q + 3] * inv);
        *(half4*)(dst + 8 * q) = o.h4;
      }
    }
  }
}

// ---------------------------------------------------------------------------
extern "C" void kernel_launch(void* const* d_in, const int* in_sizes, int n_in,
                              void* d_out, int out_size, void* d_ws, size_t ws_size,
                              hipStream_t stream) {
  const float* query = (const float*)d_in[0];
  const float* key   = (const float*)d_in[1];
  const float* value = (const float*)d_in[2];
  const float* Wq = (const float*)d_in[3];
  const float* bq = (const float*)d_in[4];
  const float* Wk = (const float*)d_in[5];
  const float* bk = (const float*)d_in[6];
  const float* Wv = (const float*)d_in[7];
  const float* bv = (const float*)d_in[8];
  const float* Wo = (const float*)d_in[9];
  const float* bo = (const float*)d_in[10];
  float* out = (float*)d_out;

  char* ws = (char*)d_ws;
  _Float16* qh    = (_Float16*)(ws);                         // [4096][2048]
  _Float16* kh    = (_Float16*)(ws + 16777216);              // [4096][2048]
  _Float16* vh    = (_Float16*)(ws + 33554432);              // [4096][2048]
  _Float16* WqkvT = (_Float16*)(ws + 50331648);              // [3072][2048]
  _Float16* WoT   = (_Float16*)(ws + 62914560);              // [2048][2048]
  _Float16* QKVh  = (_Float16*)(ws + 71303168);              // [4096][3072]
  _Float16* VT    = (_Float16*)(ws + 96468992);              // [2][8][64][2048]
  _Float16* aoh   = (_Float16*)(ws + 100663296);             // [4096][2048]

  cvt_f32_f16_3<<<dim3(4096, 1, 3), 256, 0, stream>>>(query, key, value, qh, kh, vh);
  transpose_w<<<dim3(64, 64), dim3(32, 8), 0, stream>>>(Wq, WqkvT, 2048, 2048);
  transpose_w<<<dim3(16, 64), dim3(32, 8), 0, stream>>>(Wk, WqkvT + (size_t)2048 * 2048, 512, 2048);
  transpose_w<<<dim3(16, 64), dim3(32, 8), 0, stream>>>(Wv, WqkvT + (size_t)2560 * 2048, 512, 2048);
  transpose_w<<<dim3(64, 64), dim3(32, 8), 0, stream>>>(Wo, WoT, 2048, 2048);
  gemm_f16<0><<<dim3(32, 24), 256, 0, stream>>>(qh, kh, vh, WqkvT, bq, bk, bv,
                                                QKVh, nullptr, 2048, 3072);
  transpose_v<<<dim3(64, 2, 16), dim3(32, 8), 0, stream>>>(QKVh, VT);
  attn_fwd2<<<512, 256, 0, stream>>>(QKVh, VT, aoh);
  gemm_f16<1><<<dim3(32, 16), 256, 0, stream>>>(aoh, nullptr, nullptr, WoT, bo,
                                                nullptr, nullptr, nullptr, out, 2048, 2048);
}

// Round 3
// 281.150 us; speedup vs baseline: 2.5860x; 1.8191x over previous
//
#include <hip/hip_runtime.h>
#include <cstdint>

typedef _Float16 half4 __attribute__((ext_vector_type(4)));
typedef _Float16 half8 __attribute__((ext_vector_type(8)));
typedef _Float16 half16 __attribute__((ext_vector_type(16)));
typedef float f32x4 __attribute__((ext_vector_type(4)));
typedef float f32x16 __attribute__((ext_vector_type(16)));

#define L2E 1.44269504088896340736f

__device__ __forceinline__ void gl16(const void* g, void* l) {
  __builtin_amdgcn_global_load_lds(
      (const __attribute__((address_space(1))) void*)g,
      (__attribute__((address_space(3))) void*)l, 16, 0, 0);
}

__device__ __forceinline__ uint32_t pk2(float a, float b) {
  return __builtin_bit_cast(uint32_t, __builtin_amdgcn_cvt_pkrtz(a, b));
}

__device__ __forceinline__ void plswap(uint32_t& x, uint32_t& y) {
  auto r = __builtin_amdgcn_permlane32_swap((int)x, (int)y, false, false);
  x = (uint32_t)r[0];
  y = (uint32_t)r[1];
}

__device__ __forceinline__ f32x16 zero16() {
  f32x16 z;
  #pragma unroll
  for (int r = 0; r < 16; ++r) z[r] = 0.0f;
  return z;
}

// ---------------------------------------------------------------------------
// convert fp32 -> fp16 (three activation tensors), 8 elems/thread
// ---------------------------------------------------------------------------
__global__ __launch_bounds__(256) void cvt_f32_f16_3(
    const float* __restrict__ s0, const float* __restrict__ s1, const float* __restrict__ s2,
    _Float16* __restrict__ d0, _Float16* __restrict__ d1, _Float16* __restrict__ d2)
{
  const float* src = (blockIdx.z == 0) ? s0 : (blockIdx.z == 1 ? s1 : s2);
  _Float16* dst    = (blockIdx.z == 0) ? d0 : (blockIdx.z == 1 ? d1 : d2);
  size_t i = ((size_t)blockIdx.x * 256 + threadIdx.x) * 8;
  float4 a = *(const float4*)(src + i);
  float4 b = *(const float4*)(src + i + 4);
  half8 o;
  o[0] = (_Float16)a.x; o[1] = (_Float16)a.y; o[2] = (_Float16)a.z; o[3] = (_Float16)a.w;
  o[4] = (_Float16)b.x; o[5] = (_Float16)b.y; o[6] = (_Float16)b.z; o[7] = (_Float16)b.w;
  *(half8*)(dst + i) = o;
}

// ---------------------------------------------------------------------------
// transpose + convert weight: src fp32 [K][N] (ld=N) -> dst fp16 [N][K] (ld=K)
// ---------------------------------------------------------------------------
__global__ __launch_bounds__(256) void transpose_w(
    const float* __restrict__ src, _Float16* __restrict__ dst, const int N, const int K)
{
  __shared__ float t[32][33];
  const int n0 = blockIdx.x * 32, k0 = blockIdx.y * 32;
  #pragma unroll
  for (int i = 0; i < 4; ++i)
    t[threadIdx.y + i * 8][threadIdx.x] =
        src[(size_t)(k0 + threadIdx.y + i * 8) * N + n0 + threadIdx.x];
  __syncthreads();
  #pragma unroll
  for (int i = 0; i < 4; ++i)
    dst[(size_t)(n0 + threadIdx.y + i * 8) * K + k0 + threadIdx.x] =
        (_Float16)t[threadIdx.x][threadIdx.y + i * 8];
}

// ---------------------------------------------------------------------------
// transpose V (from QKV buffer) -> VT[b][h][d][t], fp16
// ---------------------------------------------------------------------------
__global__ __launch_bounds__(256) void transpose_v(
    const _Float16* __restrict__ QKV, _Float16* __restrict__ VT)
{
  const int bh = blockIdx.z;
  const int bb = bh >> 3, h = bh & 7;
  const int t0 = blockIdx.x * 32, d0 = blockIdx.y * 32;
  __shared__ _Float16 t[32][33];
  const _Float16* src = QKV + (size_t)(bb * 2048) * 3072 + 2560 + h * 64;
  #pragma unroll
  for (int i = 0; i < 4; ++i)
    t[threadIdx.y + i * 8][threadIdx.x] =
        src[(size_t)(t0 + threadIdx.y + i * 8) * 3072 + d0 + threadIdx.x];
  __syncthreads();
  _Float16* dst = VT + ((size_t)(bb * 8 + h) * 64) * 2048;
  #pragma unroll
  for (int i = 0; i < 4; ++i)
    dst[(size_t)(d0 + threadIdx.y + i * 8) * 2048 + t0 + threadIdx.x] =
        t[threadIdx.x][threadIdx.y + i * 8];
}

// ---------------------------------------------------------------------------
// fp16 GEMM v2, C = A * B^T(+bias). 128x128 tile, BK=64, 4 waves (64x64 each).
// m97 structure: global_load_lds staging (pre-swizzled per-lane source, linear
// LDS dest), single-buffered, 2 barriers per K-step.
// Epilogue: LDS-transposed, 32B(fp16)/64B(fp32) contiguous stores per lane,
// bias applied at read time.
// MODE 0: QKV projection -> fp16 out [4096][3072], A/bias selected per n-block
// MODE 1: O projection   -> fp32 out [4096][2048]
// ---------------------------------------------------------------------------
template<int MODE>
__global__ __launch_bounds__(256) void gemm_f16(
    const _Float16* __restrict__ Aq, const _Float16* __restrict__ Ak, const _Float16* __restrict__ Av,
    const _Float16* __restrict__ Bt,
    const float* __restrict__ bias0, const float* __restrict__ bias1, const float* __restrict__ bias2,
    _Float16* __restrict__ Ch, float* __restrict__ Cf, const int K, const int N)
{
  const int m0 = blockIdx.x * 128;
  const int n0 = blockIdx.y * 128;
  const _Float16* A = Aq;
  if constexpr (MODE == 0) { if (n0 >= 2560) A = Av; else if (n0 >= 2048) A = Ak; }
  const int tid = threadIdx.x;
  const int lane = tid & 63;
  const int w = tid >> 6;
  const int wr = w >> 1, wc = w & 1;
  const int lo = lane & 15, hi = lane >> 4;

  __shared__ __align__(1024) _Float16 Asm[128 * 64];
  __shared__ __align__(1024) _Float16 Bsm[128 * 64];

  f32x4 acc[4][4];
  #pragma unroll
  for (int i = 0; i < 4; ++i)
    #pragma unroll
    for (int j = 0; j < 4; ++j)
      acc[i][j] = (f32x4){0.f, 0.f, 0.f, 0.f};

  // staging: per wave 32 rows (4 x 8); lane covers (row-in-8 li, slot lc),
  // source pre-swizzled so linear LDS dest ends up XOR-swizzled by row.
  const int li = lane >> 3;
  const int lc = lane & 7;
  const int kslot = lc ^ li;  // row&7 == li for all staged rows
  const _Float16* Asrc = A  + (size_t)(m0 + w * 32 + li) * K + kslot * 8;
  const _Float16* Bsrc = Bt + (size_t)(n0 + w * 32 + li) * K + kslot * 8;
  char* Adst = (char*)Asm + w * 4096;
  char* Bdst = (char*)Bsm + w * 4096;

  for (int k0 = 0; k0 < K; k0 += 64) {
    __syncthreads();  // previous compute's LDS reads done before overwrite
    #pragma unroll
    for (int u = 0; u < 4; ++u) {
      gl16(Asrc + k0 + (size_t)u * 8 * K, Adst + u * 1024);
      gl16(Bsrc + k0 + (size_t)u * 8 * K, Bdst + u * 1024);
    }
    __syncthreads();  // compiler drains vmcnt before barrier
    #pragma unroll
    for (int kp = 0; kp < 2; ++kp) {
      half8 af[4], bf[4];
      #pragma unroll
      for (int i = 0; i < 4; ++i) {
        const int ra = wr * 64 + i * 16 + lo;
        af[i] = *(const half8*)((const char*)Asm + ra * 128 + ((kp * 64 + hi * 16) ^ ((ra & 7) << 4)));
        const int rb = wc * 64 + i * 16 + lo;
        bf[i] = *(const half8*)((const char*)Bsm + rb * 128 + ((kp * 64 + hi * 16) ^ ((rb & 7) << 4)));
      }
      #pragma unroll
      for (int i = 0; i < 4; ++i)
        #pragma unroll
        for (int j = 0; j < 4; ++j)
          acc[i][j] = __builtin_amdgcn_mfma_f32_16x16x32_f16(af[i], bf[j], acc[i][j], 0, 0, 0);
    }
  }

  // epilogue: 4 passes through a 32x128 fp32 LDS tile (reuses Asm, 16KB),
  // then contiguous wide stores (16 cols per lane).
  float* T = (float*)Asm;
  const int tr = tid >> 3;    // 0..31
  const int slot = tid & 7;   // 0..7
  #pragma unroll
  for (int i = 0; i < 4; ++i) {
    __syncthreads();  // prior LDS use done
    #pragma unroll
    for (int j = 0; j < 4; ++j)
      #pragma unroll
      for (int r = 0; r < 4; ++r)
        T[(wr * 16 + 4 * hi + r) * 128 + wc * 64 + j * 16 + lo] = acc[i][j][r];
    __syncthreads();
    const int grow = m0 + (tr >> 4) * 64 + i * 16 + (tr & 15);
    const int gcol = n0 + slot * 16;
    const float* Trow = T + tr * 128 + slot * 16;
    float4 v[4];
    #pragma unroll
    for (int q = 0; q < 4; ++q) v[q] = ((const float4*)Trow)[q];
    const float* bp = bias0;
    int cb = gcol;
    if constexpr (MODE == 0) {
      if (gcol >= 2560) { bp = bias2; cb = gcol - 2560; }
      else if (gcol >= 2048) { bp = bias1; cb = gcol - 2048; }
    }
    float4 bvv[4];
    #pragma unroll
    for (int q = 0; q < 4; ++q) bvv[q] = ((const float4*)(bp + cb))[q];
    if constexpr (MODE == 0) {
      half16 o;
      #pragma unroll
      for (int q = 0; q < 4; ++q) {
        o[4 * q + 0] = (_Float16)(v[q].x + bvv[q].x);
        o[4 * q + 1] = (_Float16)(v[q].y + bvv[q].y);
        o[4 * q + 2] = (_Float16)(v[q].z + bvv[q].z);
        o[4 * q + 3] = (_Float16)(v[q].w + bvv[q].w);
      }
      *(half16*)(Ch + (size_t)grow * N + gcol) = o;
    } else {
      float* dst = Cf + (size_t)grow * N + gcol;
      #pragma unroll
      for (int q = 0; q < 4; ++q) {
        float4 ov = {v[q].x + bvv[q].x, v[q].y + bvv[q].y, v[q].z + bvv[q].z, v[q].w + bvv[q].w};
        ((float4*)dst)[q] = ov;
      }
    }
  }
}

// ---------------------------------------------------------------------------
// Flash attention v2 (unchanged from R2 — passed): swapped QK^T + in-register
// softmax, global_load_lds double-buffered KV staging, XCD-swizzled grid.
// ---------------------------------------------------------------------------
__global__ __launch_bounds__(256, 2) void attn_fwd2(
    const _Float16* __restrict__ QKV, const _Float16* __restrict__ VT,
    _Float16* __restrict__ AO)
{
  const int wg = blockIdx.x;
  const int work = (wg & 7) * 64 + (wg >> 3);
  const int bh = work >> 5;
  const int b = bh >> 3, h = bh & 7;
  const int rem = work & 31;
  const int qh = (rem >> 3) * 8 + h;
  const int qt = rem & 7;

  const int tid = threadIdx.x;
  const int lane = tid & 63;
  const int w = tid >> 6;
  const int l31 = lane & 31;
  const int hi5 = lane >> 5;
  const int r7 = l31 & 7;

  __shared__ __align__(1024) char sm[2][2][8192];

  const float SCALE = 0.125f * L2E;

  const int qrow0 = b * 2048 + qt * 256 + w * 64 + l31;
  half8 qf[2][4];
  #pragma unroll
  for (int qb = 0; qb < 2; ++qb) {
    const _Float16* qp = QKV + (size_t)(qrow0 + qb * 32) * 3072 + qh * 64 + hi5 * 8;
    #pragma unroll
    for (int s = 0; s < 4; ++s)
      qf[qb][s] = *(const half8*)(qp + s * 16);
  }

  const int li = lane >> 3;
  const int lc = lane & 7;
  const int kslot = lc ^ li;
  const int w16li = w * 16 + li;
  const _Float16* Ksrc = QKV + ((size_t)(b * 2048 + w16li)) * 3072 + 2048 + h * 64 + kslot * 8;
  const _Float16* Vsrc = VT + ((size_t)(b * 8 + h) * 64 + w16li) * 2048 + kslot * 8;

  f32x16 oa[2][2];
  #pragma unroll
  for (int i = 0; i < 2; ++i)
    #pragma unroll
    for (int qb = 0; qb < 2; ++qb) oa[i][qb] = zero16();
  float mreg[2] = {-3.0e38f, -3.0e38f};
  float lreg[2] = {0.f, 0.f};

  {
    char* kd = &sm[0][0][0] + w * 2048;
    char* vd = &sm[0][1][0] + w * 2048;
    gl16(Ksrc, kd);
    gl16(Ksrc + (size_t)8 * 3072, kd + 1024);
    gl16(Vsrc, vd);
    gl16(Vsrc + (size_t)8 * 2048, vd + 1024);
  }
  __syncthreads();

  int cur = 0;
  for (int t = 0; t < 32; ++t) {
    if (t < 31) {
      const int t0 = (t + 1) * 64;
      char* kd = &sm[cur ^ 1][0][0] + w * 2048;
      char* vd = &sm[cur ^ 1][1][0] + w * 2048;
      const _Float16* kg = Ksrc + (size_t)t0 * 3072;
      const _Float16* vg = Vsrc + t0;
      gl16(kg, kd);
      gl16(kg + (size_t)8 * 3072, kd + 1024);
      gl16(vg, vd);
      gl16(vg + (size_t)8 * 2048, vd + 1024);
    }

    const char* Kb = &sm[cur][0][0];
    const char* Vb = &sm[cur][1][0];

    f32x16 sa[2][2];
    #pragma unroll
    for (int j = 0; j < 2; ++j)
      #pragma unroll
      for (int qb = 0; qb < 2; ++qb) sa[j][qb] = zero16();
    #pragma unroll
    for (int s = 0; s < 4; ++s) {
      #pragma unroll
      for (int j = 0; j < 2; ++j) {
        const int kr = j * 32 + l31;
        half8 kf = *(const half8*)(Kb + kr * 128 + (((2 * s + hi5) ^ r7) << 4));
        sa[j][0] = __builtin_amdgcn_mfma_f32_32x32x16_f16(kf, qf[0][s], sa[j][0], 0, 0, 0);
        sa[j][1] = __builtin_amdgcn_mfma_f32_32x32x16_f16(kf, qf[1][s], sa[j][1], 0, 0, 0);
      }
    }

    #pragma unroll
    for (int qb = 0; qb < 2; ++qb) {
      float pm = -3.0e38f;
      #pragma unroll
      for (int j = 0; j < 2; ++j)
        #pragma unroll
        for (int r = 0; r < 16; ++r) {
          const float v = sa[j][qb][r] * SCALE;
          sa[j][qb][r] = v;
          pm = fmaxf(pm, v);
        }
      pm = fmaxf(pm, __shfl_xor(pm, 32));
      const float mnew = fmaxf(mreg[qb], pm);
      const float corr = __builtin_amdgcn_exp2f(mreg[qb] - mnew);
      mreg[qb] = mnew;
      float ps = 0.f;
      #pragma unroll
      for (int j = 0; j < 2; ++j)
        #pragma unroll
        for (int r = 0; r < 16; ++r) {
          const float p = __builtin_amdgcn_exp2f(sa[j][qb][r] - mnew);
          sa[j][qb][r] = p;
          ps += p;
        }
      ps += __shfl_xor(ps, 32);
      lreg[qb] = lreg[qb] * corr + ps;
      #pragma unroll
      for (int i = 0; i < 2; ++i)
        #pragma unroll
        for (int r = 0; r < 16; ++r)
          oa[i][qb][r] *= corr;
    }

    uint32_t pw[2][4][4];
    #pragma unroll
    for (int qb = 0; qb < 2; ++qb)
      #pragma unroll
      for (int j = 0; j < 2; ++j)
        #pragma unroll
        for (int hf = 0; hf < 2; ++hf) {
          const int rb = hf * 8;
          uint32_t w0 = pk2(sa[j][qb][rb + 0], sa[j][qb][rb + 1]);
          uint32_t w1 = pk2(sa[j][qb][rb + 2], sa[j][qb][rb + 3]);
          uint32_t w2 = pk2(sa[j][qb][rb + 4], sa[j][qb][rb + 5]);
          uint32_t w3 = pk2(sa[j][qb][rb + 6], sa[j][qb][rb + 7]);
          plswap(w0, w2);
          plswap(w1, w3);
          const int s = 2 * j + hf;
          pw[qb][s][0] = w0; pw[qb][s][1] = w1; pw[qb][s][2] = w2; pw[qb][s][3] = w3;
        }

    #pragma unroll
    for (int s = 0; s < 4; ++s) {
      union { uint32_t u[4]; half8 h; } p0, p1;
      #pragma unroll
      for (int u = 0; u < 4; ++u) { p0.u[u] = pw[0][s][u]; p1.u[u] = pw[1][s][u]; }
      #pragma unroll
      for (int i = 0; i < 2; ++i) {
        const int vr = i * 32 + l31;
        half8 vf = *(const half8*)(Vb + vr * 128 + (((2 * s + hi5) ^ r7) << 4));
        oa[i][0] = __builtin_amdgcn_mfma_f32_32x32x16_f16(vf, p0.h, oa[i][0], 0, 0, 0);
        oa[i][1] = __builtin_amdgcn_mfma_f32_32x32x16_f16(vf, p1.h, oa[i][1], 0, 0, 0);
      }
    }

    __syncthreads();
    cur ^= 1;
  }

  #pragma unroll
  for (int qb = 0; qb < 2; ++qb) {
    const float inv = 1.0f / lreg[qb];
    const int row = qrow0 + qb * 32;
    #pragma unroll
    for (int i = 0; i < 2; ++i) {
      _Float16* dst = AO + (size_t)row * 2048 + qh * 64 + i * 32 + hi5 * 4;
      #pragma unroll
      for (int q = 0; q < 4; ++q) {
        union { uint32_t u[2]; half4 h4; } o;
        o.u[0] = pk2(oa[i][qb][4 * q + 0] * inv, oa[i][qb][4 * q + 1] * inv);
        o.u[1] = pk2(oa[i][qb][4 * q + 2] * inv, oa[i][qb][4 * q + 3] * inv);
        *(half4*)(dst + 8 * q) = o.h4;
      }
    }
  }
}

// ---------------------------------------------------------------------------
extern "C" void kernel_launch(void* const* d_in, const int* in_sizes, int n_in,
                              void* d_out, int out_size, void* d_ws, size_t ws_size,
                              hipStream_t stream) {
  const float* query = (const float*)d_in[0];
  const float* key   = (const float*)d_in[1];
  const float* value = (const float*)d_in[2];
  const float* Wq = (const float*)d_in[3];
  const float* bq = (const float*)d_in[4];
  const float* Wk = (const float*)d_in[5];
  const float* bk = (const float*)d_in[6];
  const float* Wv = (const float*)d_in[7];
  const float* bv = (const float*)d_in[8];
  const float* Wo = (const float*)d_in[9];
  const float* bo = (const float*)d_in[10];
  float* out = (float*)d_out;

  char* ws = (char*)d_ws;
  _Float16* qh    = (_Float16*)(ws);                         // [4096][2048]
  _Float16* kh    = (_Float16*)(ws + 16777216);              // [4096][2048]
  _Float16* vh    = (_Float16*)(ws + 33554432);              // [4096][2048]
  _Float16* WqkvT = (_Float16*)(ws + 50331648);              // [3072][2048]
  _Float16* WoT   = (_Float16*)(ws + 62914560);              // [2048][2048]
  _Float16* QKVh  = (_Float16*)(ws + 71303168);              // [4096][3072]
  _Float16* VT    = (_Float16*)(ws + 96468992);              // [2][8][64][2048]
  _Float16* aoh   = (_Float16*)(ws + 100663296);             // [4096][2048]

  cvt_f32_f16_3<<<dim3(4096, 1, 3), 256, 0, stream>>>(query, key, value, qh, kh, vh);
  transpose_w<<<dim3(64, 64), dim3(32, 8), 0, stream>>>(Wq, WqkvT, 2048, 2048);
  transpose_w<<<dim3(16, 64), dim3(32, 8), 0, stream>>>(Wk, WqkvT + (size_t)2048 * 2048, 512, 2048);
  transpose_w<<<dim3(16, 64), dim3(32, 8), 0, stream>>>(Wv, WqkvT + (size_t)2560 * 2048, 512, 2048);
  transpose_w<<<dim3(64, 64), dim3(32, 8), 0, stream>>>(Wo, WoT, 2048, 2048);
  gemm_f16<0><<<dim3(32, 24), 256, 0, stream>>>(qh, kh, vh, WqkvT, bq, bk, bv,
                                                QKVh, nullptr, 2048, 3072);
  transpose_v<<<dim3(64, 2, 16), dim3(32, 8), 0, stream>>>(QKVh, VT);
  attn_fwd2<<<512, 256, 0, stream>>>(QKVh, VT, aoh);
  gemm_f16<1><<<dim3(32, 16), 256, 0, stream>>>(aoh, nullptr, nullptr, WoT, bo,
                                                nullptr, nullptr, nullptr, out, 2048, 2048);
}

// Round 4
// 265.119 us; speedup vs baseline: 2.7424x; 1.0605x over previous
//
#include <hip/hip_runtime.h>
#include <cstdint>

typedef _Float16 half4 __attribute__((ext_vector_type(4)));
typedef _Float16 half8 __attribute__((ext_vector_type(8)));
typedef _Float16 half16 __attribute__((ext_vector_type(16)));
typedef float f32x4 __attribute__((ext_vector_type(4)));
typedef float f32x16 __attribute__((ext_vector_type(16)));

#define L2E 1.44269504088896340736f

__device__ __forceinline__ void gl16(const void* g, void* l) {
  __builtin_amdgcn_global_load_lds(
      (const __attribute__((address_space(1))) void*)g,
      (__attribute__((address_space(3))) void*)l, 16, 0, 0);
}

__device__ __forceinline__ uint32_t pk2(float a, float b) {
  return __builtin_bit_cast(uint32_t, __builtin_amdgcn_cvt_pkrtz(a, b));
}

__device__ __forceinline__ void plswap(uint32_t& x, uint32_t& y) {
  auto r = __builtin_amdgcn_permlane32_swap((int)x, (int)y, false, false);
  x = (uint32_t)r[0];
  y = (uint32_t)r[1];
}

__device__ __forceinline__ f32x16 zero16() {
  f32x16 z;
  #pragma unroll
  for (int r = 0; r < 16; ++r) z[r] = 0.0f;
  return z;
}

// ---------------------------------------------------------------------------
// convert fp32 -> fp16 (three activation tensors), 8 elems/thread
// ---------------------------------------------------------------------------
__global__ __launch_bounds__(256) void cvt_f32_f16_3(
    const float* __restrict__ s0, const float* __restrict__ s1, const float* __restrict__ s2,
    _Float16* __restrict__ d0, _Float16* __restrict__ d1, _Float16* __restrict__ d2)
{
  const float* src = (blockIdx.z == 0) ? s0 : (blockIdx.z == 1 ? s1 : s2);
  _Float16* dst    = (blockIdx.z == 0) ? d0 : (blockIdx.z == 1 ? d1 : d2);
  size_t i = ((size_t)blockIdx.x * 256 + threadIdx.x) * 8;
  float4 a = *(const float4*)(src + i);
  float4 b = *(const float4*)(src + i + 4);
  half8 o;
  o[0] = (_Float16)a.x; o[1] = (_Float16)a.y; o[2] = (_Float16)a.z; o[3] = (_Float16)a.w;
  o[4] = (_Float16)b.x; o[5] = (_Float16)b.y; o[6] = (_Float16)b.z; o[7] = (_Float16)b.w;
  *(half8*)(dst + i) = o;
}

// ---------------------------------------------------------------------------
// transpose + convert ALL weights in one launch: src fp32 [K=2048][N] ->
// dst fp16 [N][2048]. 10240 tiles of 32x32, flat-indexed, block (32,8).
// id 0..4095: Wq -> WqkvT[0:2048]; 4096..5119: Wk -> WqkvT[2048:2560];
// 5120..6143: Wv -> WqkvT[2560:3072]; 6144..10239: Wo -> WoT.
// ---------------------------------------------------------------------------
__global__ __launch_bounds__(256) void transpose_w_all(
    const float* __restrict__ Wq, const float* __restrict__ Wk,
    const float* __restrict__ Wv, const float* __restrict__ Wo,
    _Float16* __restrict__ WqkvT, _Float16* __restrict__ WoT)
{
  int id = blockIdx.x;
  const float* src;
  _Float16* dst;
  int N, tx, ty;
  if (id < 4096)      { src = Wq; dst = WqkvT;                        N = 2048; tx = id & 63; ty = id >> 6; }
  else if (id < 5120) { id -= 4096; src = Wk; dst = WqkvT + (size_t)2048 * 2048; N = 512; tx = id & 15; ty = id >> 4; }
  else if (id < 6144) { id -= 5120; src = Wv; dst = WqkvT + (size_t)2560 * 2048; N = 512; tx = id & 15; ty = id >> 4; }
  else                { id -= 6144; src = Wo; dst = WoT;              N = 2048; tx = id & 63; ty = id >> 6; }
  const int n0 = tx * 32, k0 = ty * 32;
  __shared__ float t[32][33];
  #pragma unroll
  for (int i = 0; i < 4; ++i)
    t[threadIdx.y + i * 8][threadIdx.x] =
        src[(size_t)(k0 + threadIdx.y + i * 8) * N + n0 + threadIdx.x];
  __syncthreads();
  #pragma unroll
  for (int i = 0; i < 4; ++i)
    dst[(size_t)(n0 + threadIdx.y + i * 8) * 2048 + k0 + threadIdx.x] =
        (_Float16)t[threadIdx.x][threadIdx.y + i * 8];
}

// ---------------------------------------------------------------------------
// transpose V (from QKV buffer) -> VT[b][h][d][t], fp16
// ---------------------------------------------------------------------------
__global__ __launch_bounds__(256) void transpose_v(
    const _Float16* __restrict__ QKV, _Float16* __restrict__ VT)
{
  const int bh = blockIdx.z;
  const int bb = bh >> 3, h = bh & 7;
  const int t0 = blockIdx.x * 32, d0 = blockIdx.y * 32;
  __shared__ _Float16 t[32][33];
  const _Float16* src = QKV + (size_t)(bb * 2048) * 3072 + 2560 + h * 64;
  #pragma unroll
  for (int i = 0; i < 4; ++i)
    t[threadIdx.y + i * 8][threadIdx.x] =
        src[(size_t)(t0 + threadIdx.y + i * 8) * 3072 + d0 + threadIdx.x];
  __syncthreads();
  _Float16* dst = VT + ((size_t)(bb * 8 + h) * 64) * 2048;
  #pragma unroll
  for (int i = 0; i < 4; ++i)
    dst[(size_t)(d0 + threadIdx.y + i * 8) * 2048 + t0 + threadIdx.x] =
        t[threadIdx.x][threadIdx.y + i * 8];
}

// ---------------------------------------------------------------------------
// fp16 GEMM v2 (unchanged from R3 — passed): 128x128 tile, BK=64, 4 waves,
// global_load_lds staging, LDS-transposed wide-store epilogue.
// ---------------------------------------------------------------------------
template<int MODE>
__global__ __launch_bounds__(256) void gemm_f16(
    const _Float16* __restrict__ Aq, const _Float16* __restrict__ Ak, const _Float16* __restrict__ Av,
    const _Float16* __restrict__ Bt,
    const float* __restrict__ bias0, const float* __restrict__ bias1, const float* __restrict__ bias2,
    _Float16* __restrict__ Ch, float* __restrict__ Cf, const int K, const int N)
{
  const int m0 = blockIdx.x * 128;
  const int n0 = blockIdx.y * 128;
  const _Float16* A = Aq;
  if constexpr (MODE == 0) { if (n0 >= 2560) A = Av; else if (n0 >= 2048) A = Ak; }
  const int tid = threadIdx.x;
  const int lane = tid & 63;
  const int w = tid >> 6;
  const int wr = w >> 1, wc = w & 1;
  const int lo = lane & 15, hi = lane >> 4;

  __shared__ __align__(1024) _Float16 Asm[128 * 64];
  __shared__ __align__(1024) _Float16 Bsm[128 * 64];

  f32x4 acc[4][4];
  #pragma unroll
  for (int i = 0; i < 4; ++i)
    #pragma unroll
    for (int j = 0; j < 4; ++j)
      acc[i][j] = (f32x4){0.f, 0.f, 0.f, 0.f};

  const int li = lane >> 3;
  const int lc = lane & 7;
  const int kslot = lc ^ li;
  const _Float16* Asrc = A  + (size_t)(m0 + w * 32 + li) * K + kslot * 8;
  const _Float16* Bsrc = Bt + (size_t)(n0 + w * 32 + li) * K + kslot * 8;
  char* Adst = (char*)Asm + w * 4096;
  char* Bdst = (char*)Bsm + w * 4096;

  for (int k0 = 0; k0 < K; k0 += 64) {
    __syncthreads();
    #pragma unroll
    for (int u = 0; u < 4; ++u) {
      gl16(Asrc + k0 + (size_t)u * 8 * K, Adst + u * 1024);
      gl16(Bsrc + k0 + (size_t)u * 8 * K, Bdst + u * 1024);
    }
    __syncthreads();
    #pragma unroll
    for (int kp = 0; kp < 2; ++kp) {
      half8 af[4], bf[4];
      #pragma unroll
      for (int i = 0; i < 4; ++i) {
        const int ra = wr * 64 + i * 16 + lo;
        af[i] = *(const half8*)((const char*)Asm + ra * 128 + ((kp * 64 + hi * 16) ^ ((ra & 7) << 4)));
        const int rb = wc * 64 + i * 16 + lo;
        bf[i] = *(const half8*)((const char*)Bsm + rb * 128 + ((kp * 64 + hi * 16) ^ ((rb & 7) << 4)));
      }
      #pragma unroll
      for (int i = 0; i < 4; ++i)
        #pragma unroll
        for (int j = 0; j < 4; ++j)
          acc[i][j] = __builtin_amdgcn_mfma_f32_16x16x32_f16(af[i], bf[j], acc[i][j], 0, 0, 0);
    }
  }

  float* T = (float*)Asm;
  const int tr = tid >> 3;
  const int slot = tid & 7;
  #pragma unroll
  for (int i = 0; i < 4; ++i) {
    __syncthreads();
    #pragma unroll
    for (int j = 0; j < 4; ++j)
      #pragma unroll
      for (int r = 0; r < 4; ++r)
        T[(wr * 16 + 4 * hi + r) * 128 + wc * 64 + j * 16 + lo] = acc[i][j][r];
    __syncthreads();
    const int grow = m0 + (tr >> 4) * 64 + i * 16 + (tr & 15);
    const int gcol = n0 + slot * 16;
    const float* Trow = T + tr * 128 + slot * 16;
    float4 v[4];
    #pragma unroll
    for (int q = 0; q < 4; ++q) v[q] = ((const float4*)Trow)[q];
    const float* bp = bias0;
    int cb = gcol;
    if constexpr (MODE == 0) {
      if (gcol >= 2560) { bp = bias2; cb = gcol - 2560; }
      else if (gcol >= 2048) { bp = bias1; cb = gcol - 2048; }
    }
    float4 bvv[4];
    #pragma unroll
    for (int q = 0; q < 4; ++q) bvv[q] = ((const float4*)(bp + cb))[q];
    if constexpr (MODE == 0) {
      half16 o;
      #pragma unroll
      for (int q = 0; q < 4; ++q) {
        o[4 * q + 0] = (_Float16)(v[q].x + bvv[q].x);
        o[4 * q + 1] = (_Float16)(v[q].y + bvv[q].y);
        o[4 * q + 2] = (_Float16)(v[q].z + bvv[q].z);
        o[4 * q + 3] = (_Float16)(v[q].w + bvv[q].w);
      }
      *(half16*)(Ch + (size_t)grow * N + gcol) = o;
    } else {
      float* dst = Cf + (size_t)grow * N + gcol;
      #pragma unroll
      for (int q = 0; q < 4; ++q) {
        float4 ov = {v[q].x + bvv[q].x, v[q].y + bvv[q].y, v[q].z + bvv[q].z, v[q].w + bvv[q].w};
        ((float4*)dst)[q] = ov;
      }
    }
  }
}

// ---------------------------------------------------------------------------
// Flash attention v3: v2 + VALU diet.
//  - 0.125 softmax scale folded into Q fragments (exact in fp16)
//  - defer-max (T13): skip rescale unless __any(pm - m > 5.5); exp arg <= 8
//  - exp via single FMA against cached mn2 = m * log2(e)
//  - s_setprio(1) around MFMA clusters (T5)
// ---------------------------------------------------------------------------
__global__ __launch_bounds__(256, 2) void attn_fwd3(
    const _Float16* __restrict__ QKV, const _Float16* __restrict__ VT,
    _Float16* __restrict__ AO)
{
  const int wg = blockIdx.x;
  const int work = (wg & 7) * 64 + (wg >> 3);
  const int bh = work >> 5;
  const int b = bh >> 3, h = bh & 7;
  const int rem = work & 31;
  const int qh = (rem >> 3) * 8 + h;
  const int qt = rem & 7;

  const int tid = threadIdx.x;
  const int lane = tid & 63;
  const int w = tid >> 6;
  const int l31 = lane & 31;
  const int hi5 = lane >> 5;
  const int r7 = l31 & 7;

  __shared__ __align__(1024) char sm[2][2][8192];

  // Q fragments, pre-scaled by 0.125 (exact in fp16)
  const int qrow0 = b * 2048 + qt * 256 + w * 64 + l31;
  half8 qf[2][4];
  #pragma unroll
  for (int qb = 0; qb < 2; ++qb) {
    const _Float16* qp = QKV + (size_t)(qrow0 + qb * 32) * 3072 + qh * 64 + hi5 * 8;
    #pragma unroll
    for (int s = 0; s < 4; ++s) {
      half8 q = *(const half8*)(qp + s * 16);
      #pragma unroll
      for (int e = 0; e < 8; ++e) q[e] = q[e] * (_Float16)0.125f;
      qf[qb][s] = q;
    }
  }

  const int li = lane >> 3;
  const int lc = lane & 7;
  const int kslot = lc ^ li;
  const int w16li = w * 16 + li;
  const _Float16* Ksrc = QKV + ((size_t)(b * 2048 + w16li)) * 3072 + 2048 + h * 64 + kslot * 8;
  const _Float16* Vsrc = VT + ((size_t)(b * 8 + h) * 64 + w16li) * 2048 + kslot * 8;

  f32x16 oa[2][2];
  #pragma unroll
  for (int i = 0; i < 2; ++i)
    #pragma unroll
    for (int qb = 0; qb < 2; ++qb) oa[i][qb] = zero16();
  float mreg[2] = {-1.0e30f, -1.0e30f};
  float mn2[2]  = {-1.0e30f, -1.0e30f};
  float lreg[2] = {0.f, 0.f};

  {
    char* kd = &sm[0][0][0] + w * 2048;
    char* vd = &sm[0][1][0] + w * 2048;
    gl16(Ksrc, kd);
    gl16(Ksrc + (size_t)8 * 3072, kd + 1024);
    gl16(Vsrc, vd);
    gl16(Vsrc + (size_t)8 * 2048, vd + 1024);
  }
  __syncthreads();

  int cur = 0;
  for (int t = 0; t < 32; ++t) {
    if (t < 31) {
      const int t0 = (t + 1) * 64;
      char* kd = &sm[cur ^ 1][0][0] + w * 2048;
      char* vd = &sm[cur ^ 1][1][0] + w * 2048;
      const _Float16* kg = Ksrc + (size_t)t0 * 3072;
      const _Float16* vg = Vsrc + t0;
      gl16(kg, kd);
      gl16(kg + (size_t)8 * 3072, kd + 1024);
      gl16(vg, vd);
      gl16(vg + (size_t)8 * 2048, vd + 1024);
    }

    const char* Kb = &sm[cur][0][0];
    const char* Vb = &sm[cur][1][0];

    // S^T = K Q^T (pre-scaled)
    f32x16 sa[2][2];
    #pragma unroll
    for (int j = 0; j < 2; ++j)
      #pragma unroll
      for (int qb = 0; qb < 2; ++qb) sa[j][qb] = zero16();
    __builtin_amdgcn_s_setprio(1);
    #pragma unroll
    for (int s = 0; s < 4; ++s) {
      #pragma unroll
      for (int j = 0; j < 2; ++j) {
        const int kr = j * 32 + l31;
        half8 kf = *(const half8*)(Kb + kr * 128 + (((2 * s + hi5) ^ r7) << 4));
        sa[j][0] = __builtin_amdgcn_mfma_f32_32x32x16_f16(kf, qf[0][s], sa[j][0], 0, 0, 0);
        sa[j][1] = __builtin_amdgcn_mfma_f32_32x32x16_f16(kf, qf[1][s], sa[j][1], 0, 0, 0);
      }
    }
    __builtin_amdgcn_s_setprio(0);

    // online softmax with defer-max
    #pragma unroll
    for (int qb = 0; qb < 2; ++qb) {
      float pm = -1.0e30f;
      #pragma unroll
      for (int j = 0; j < 2; ++j)
        #pragma unroll
        for (int r = 0; r < 16; ++r)
          pm = fmaxf(pm, sa[j][qb][r]);
      pm = fmaxf(pm, __shfl_xor(pm, 32));
      if (__any(pm - mreg[qb] > 5.5f)) {
        const float mnew = fmaxf(mreg[qb], pm);
        const float corr = __builtin_amdgcn_exp2f((mreg[qb] - mnew) * L2E);
        mreg[qb] = mnew;
        mn2[qb] = mnew * L2E;
        lreg[qb] *= corr;
        #pragma unroll
        for (int i = 0; i < 2; ++i)
          #pragma unroll
          for (int r = 0; r < 16; ++r)
            oa[i][qb][r] *= corr;
      }
      const float nmn2 = -mn2[qb];
      float ps = 0.f;
      #pragma unroll
      for (int j = 0; j < 2; ++j)
        #pragma unroll
        for (int r = 0; r < 16; ++r) {
          const float p = __builtin_amdgcn_exp2f(fmaf(sa[j][qb][r], L2E, nmn2));
          sa[j][qb][r] = p;
          ps += p;
        }
      ps += __shfl_xor(ps, 32);
      lreg[qb] += ps;
    }

    // pack P -> fp16 B-frags (T12)
    uint32_t pw[2][4][4];
    #pragma unroll
    for (int qb = 0; qb < 2; ++qb)
      #pragma unroll
      for (int j = 0; j < 2; ++j)
        #pragma unroll
        for (int hf = 0; hf < 2; ++hf) {
          const int rb = hf * 8;
          uint32_t w0 = pk2(sa[j][qb][rb + 0], sa[j][qb][rb + 1]);
          uint32_t w1 = pk2(sa[j][qb][rb + 2], sa[j][qb][rb + 3]);
          uint32_t w2 = pk2(sa[j][qb][rb + 4], sa[j][qb][rb + 5]);
          uint32_t w3 = pk2(sa[j][qb][rb + 6], sa[j][qb][rb + 7]);
          plswap(w0, w2);
          plswap(w1, w3);
          const int s = 2 * j + hf;
          pw[qb][s][0] = w0; pw[qb][s][1] = w1; pw[qb][s][2] = w2; pw[qb][s][3] = w3;
        }

    // PV: O^T += V^T P^T
    __builtin_amdgcn_s_setprio(1);
    #pragma unroll
    for (int s = 0; s < 4; ++s) {
      union { uint32_t u[4]; half8 h; } p0, p1;
      #pragma unroll
      for (int u = 0; u < 4; ++u) { p0.u[u] = pw[0][s][u]; p1.u[u] = pw[1][s][u]; }
      #pragma unroll
      for (int i = 0; i < 2; ++i) {
        const int vr = i * 32 + l31;
        half8 vf = *(const half8*)(Vb + vr * 128 + (((2 * s + hi5) ^ r7) << 4));
        oa[i][0] = __builtin_amdgcn_mfma_f32_32x32x16_f16(vf, p0.h, oa[i][0], 0, 0, 0);
        oa[i][1] = __builtin_amdgcn_mfma_f32_32x32x16_f16(vf, p1.h, oa[i][1], 0, 0, 0);
      }
    }
    __builtin_amdgcn_s_setprio(0);

    __syncthreads();
    cur ^= 1;
  }

  #pragma unroll
  for (int qb = 0; qb < 2; ++qb) {
    const float inv = 1.0f / lreg[qb];
    const int row = qrow0 + qb * 32;
    #pragma unroll
    for (int i = 0; i < 2; ++i) {
      _Float16* dst = AO + (size_t)row * 2048 + qh * 64 + i * 32 + hi5 * 4;
      #pragma unroll
      for (int q = 0; q < 4; ++q) {
        union { uint32_t u[2]; half4 h4; } o;
        o.u[0] = pk2(oa[i][qb][4 * q + 0] * inv, oa[i][qb][4 * q + 1] * inv);
        o.u[1] = pk2(oa[i][qb][4 * q + 2] * inv, oa[i][qb][4 * q + 3] * inv);
        *(half4*)(dst + 8 * q) = o.h4;
      }
    }
  }
}

// ---------------------------------------------------------------------------
extern "C" void kernel_launch(void* const* d_in, const int* in_sizes, int n_in,
                              void* d_out, int out_size, void* d_ws, size_t ws_size,
                              hipStream_t stream) {
  const float* query = (const float*)d_in[0];
  const float* key   = (const float*)d_in[1];
  const float* value = (const float*)d_in[2];
  const float* Wq = (const float*)d_in[3];
  const float* bq = (const float*)d_in[4];
  const float* Wk = (const float*)d_in[5];
  const float* bk = (const float*)d_in[6];
  const float* Wv = (const float*)d_in[7];
  const float* bv = (const float*)d_in[8];
  const float* Wo = (const float*)d_in[9];
  const float* bo = (const float*)d_in[10];
  float* out = (float*)d_out;

  char* ws = (char*)d_ws;
  _Float16* qh    = (_Float16*)(ws);                         // [4096][2048]
  _Float16* kh    = (_Float16*)(ws + 16777216);              // [4096][2048]
  _Float16* vh    = (_Float16*)(ws + 33554432);              // [4096][2048]
  _Float16* WqkvT = (_Float16*)(ws + 50331648);              // [3072][2048]
  _Float16* WoT   = (_Float16*)(ws + 62914560);              // [2048][2048]
  _Float16* QKVh  = (_Float16*)(ws + 71303168);              // [4096][3072]
  _Float16* VT    = (_Float16*)(ws + 96468992);              // [2][8][64][2048]
  _Float16* aoh   = (_Float16*)(ws + 100663296);             // [4096][2048]

  cvt_f32_f16_3<<<dim3(4096, 1, 3), 256, 0, stream>>>(query, key, value, qh, kh, vh);
  transpose_w_all<<<10240, dim3(32, 8), 0, stream>>>(Wq, Wk, Wv, Wo, WqkvT, WoT);
  gemm_f16<0><<<dim3(32, 24), 256, 0, stream>>>(qh, kh, vh, WqkvT, bq, bk, bv,
                                                QKVh, nullptr, 2048, 3072);
  transpose_v<<<dim3(64, 2, 16), dim3(32, 8), 0, stream>>>(QKVh, VT);
  attn_fwd3<<<512, 256, 0, stream>>>(QKVh, VT, aoh);
  gemm_f16<1><<<dim3(32, 16), 256, 0, stream>>>(aoh, nullptr, nullptr, WoT, bo,
                                                nullptr, nullptr, nullptr, out, 2048, 2048);
}